// Round 17
// baseline (1024.178 us; speedup 1.0000x reference)
//
#include <hip/hip_runtime.h>

#define HID 2048
#define INTER 1408
#define NEXP 14
#define SINTER 2816
#define TTOK 2048
#define BK 64

#define GLU_RT 154   // 14 e x 11 nt (routed first: 2 m-iters each)
#define GLU_SH 176   // 22 nt x 8 m-slices (256 rows each)
#define DWN_SH 64    // 8 nt x 8 m-slices (256 rows each)
#define DWN_RT 112   // 14 e x 8 nt (in-block m-loop)

typedef short bf16x8 __attribute__((ext_vector_type(8)));
typedef float f32x4 __attribute__((ext_vector_type(4)));
typedef unsigned short u16x8 __attribute__((ext_vector_type(8)));

__device__ __forceinline__ unsigned short f2bf(float f) {
    __bf16 b = (__bf16)f;
    return __builtin_bit_cast(unsigned short, b);
}
__device__ __forceinline__ float bf2f(unsigned short u) {
    unsigned v = (unsigned)u << 16;
    return __builtin_bit_cast(float, v);
}
// proven conflict-free swizzles: 128B rows (K-tiles), 256B rows (epilogue)
__device__ __forceinline__ unsigned swz(unsigned b)    { return b ^ (((b >> 7) & 7u) << 4); }
__device__ __forceinline__ unsigned swz256(unsigned b) { return b ^ (((b >> 8) & 7u) << 4); }

__device__ __forceinline__ void gload16(const void* g, void* l) {
    __builtin_amdgcn_global_load_lds((__attribute__((address_space(1))) void*)g,
                                     (__attribute__((address_space(3))) void*)l, 16, 0, 0);
}
__device__ __forceinline__ void bsync() {
    __builtin_amdgcn_sched_barrier(0);
    __builtin_amdgcn_s_barrier();
    __builtin_amdgcn_sched_barrier(0);
}
#define WAIT_LGKM0 asm volatile("s_waitcnt lgkmcnt(0)" ::: "memory")
#define MFMA16(a, b, c) __builtin_amdgcn_mfma_f32_16x16x32_bf16(a, b, c, 0, 0, 0)

__global__ void k_zero(int* cnt) {
    if ((int)threadIdx.x < NEXP) cnt[threadIdx.x] = 0;
}

// Router, vectorized (R11-proven) + fused x->bf16 store.
__global__ __launch_bounds__(256, 4) void k_router(
    const float* __restrict__ x,
    const float* __restrict__ gate_w, const float* __restrict__ cls_w,
    const float* __restrict__ escale, const float* __restrict__ ebias,
    int* __restrict__ cnt, int* __restrict__ etok, float* __restrict__ ew,
    unsigned short* __restrict__ xb) {
    const int lane = threadIdx.x & 63;
    const int tok = blockIdx.x * 4 + (threadIdx.x >> 6);
    const float* xr = x + (size_t)tok * HID + lane * 4;
    float4 xv[8];
#pragma unroll
    for (int i = 0; i < 8; i++) xv[i] = *(const float4*)(xr + i * 256);
    unsigned short* xbr = xb + (size_t)tok * HID + lane * 4;
#pragma unroll
    for (int i = 0; i < 8; i++) {
        ushort4 v;
        v.x = f2bf(xv[i].x); v.y = f2bf(xv[i].y);
        v.z = f2bf(xv[i].z); v.w = f2bf(xv[i].w);
        *(ushort4*)(xbr + i * 256) = v;
    }

    float sc[NEXP];
    float mx = 0.f;
#pragma unroll
    for (int e = 0; e < NEXP; e++) {
        const float* cw = cls_w + (size_t)e * HID + lane * 4;
        const float* gw = gate_w + (size_t)e * HID + lane * 4;
        float pc = 0.f, pg = 0.f;
        {
            float4 cv[8];
#pragma unroll
            for (int i = 0; i < 8; i++) cv[i] = *(const float4*)(cw + i * 256);
#pragma unroll
            for (int i = 0; i < 8; i++) {
                pc = fmaf(xv[i].x, cv[i].x, pc);
                pc = fmaf(xv[i].y, cv[i].y, pc);
                pc = fmaf(xv[i].z, cv[i].z, pc);
                pc = fmaf(xv[i].w, cv[i].w, pc);
            }
        }
        {
            float4 gv[8];
#pragma unroll
            for (int i = 0; i < 8; i++) gv[i] = *(const float4*)(gw + i * 256);
#pragma unroll
            for (int i = 0; i < 8; i++) {
                pg = fmaf(xv[i].x, gv[i].x, pg);
                pg = fmaf(xv[i].y, gv[i].y, pg);
                pg = fmaf(xv[i].z, gv[i].z, pg);
                pg = fmaf(xv[i].w, gv[i].w, pg);
            }
        }
#pragma unroll
        for (int o = 32; o >= 1; o >>= 1) {
            pc += __shfl_xor(pc, o);
            pg += __shfl_xor(pg, o);
        }
        float lg = pc * (pg / (1.f + __expf(-pg)));
        sc[e] = fabsf(lg);
        mx = fmaxf(mx, sc[e]);
    }
    float s = 0.f;
#pragma unroll
    for (int e = 0; e < NEXP; e++) { sc[e] = __expf(sc[e] - mx); s += sc[e]; }
    float inv = 1.f / s;
    int i1 = -1, i2 = -1;
    float b1 = -1e30f, b2 = -1e30f, v1 = 0.f, v2 = 0.f;
#pragma unroll
    for (int e = 0; e < NEXP; e++) {
        float sv = sc[e] * inv;
        float b = sv + ebias[e];
        if (b > b1) { b2 = b1; i2 = i1; v2 = v1; b1 = b; i1 = e; v1 = sv; }
        else if (b > b2) { b2 = b; i2 = e; v2 = sv; }
    }
    if (lane == 0) {
        float w1 = 1.f + v1 * escale[i1];
        float w2 = 1.f + v2 * escale[i2];
        int p1 = atomicAdd(&cnt[i1], 1);
        etok[i1 * TTOK + p1] = tok * 2;     ew[i1 * TTOK + p1] = w1;
        int p2 = atomicAdd(&cnt[i2], 1);
        etok[i2 * TTOK + p2] = tok * 2 + 1; ew[i2 * TTOK + p2] = w2;
    }
}

__global__ void k_offsets(const int* __restrict__ cnt, int* __restrict__ offs) {
    if (threadIdx.x == 0) {
        int a = 0;
        for (int e = 0; e < NEXP; e++) { offs[e] = a; a += cnt[e]; }
    }
}

// Gate+up GEMM. BM=256, BN=128(G)+128(U), BK=64, 1024 thr / 16 waves (8m x 2n).
// A: dbuf via global_load_lds. B: fp32 -> bf16 reg-carried one iter.
__global__ __launch_bounds__(1024, 4) void k_glu17(
    const unsigned short* __restrict__ xb,
    const float* __restrict__ wg, const float* __restrict__ wu,
    const float* __restrict__ sg, const float* __restrict__ su,
    unsigned short* __restrict__ abuf, unsigned short* __restrict__ hbuf,
    const int* __restrict__ cnt, const int* __restrict__ offs,
    const int* __restrict__ etok) {
    __shared__ alignas(16) unsigned short sA[2][256 * BK];  // 2 x 32 KB
    __shared__ alignas(16) unsigned short sBg[128 * BK];    // 16 KB
    __shared__ alignas(16) unsigned short sBu[128 * BK];    // 16 KB

    const int bx = blockIdx.x, t = threadIdx.x;
    const int lane = t & 63, w = t >> 6;
    const int wm = w >> 1, wn = w & 1;
    const int fr = lane & 15, fo = lane >> 4;

    const bool routed = bx < GLU_RT;
    int n0, m_start, m_stop, obase, Ntot;
    const float *Bg, *Bu;
    unsigned short* outp;
    const int* etk = nullptr;
    if (routed) {
        int e = bx / 11; n0 = (bx % 11) * 128;
        int M = cnt[e];
        if (M <= 0) return;
        m_start = 0; m_stop = M; obase = offs[e]; Ntot = INTER;
        Bg = wg + ((size_t)e * INTER + n0) * HID;
        Bu = wu + ((size_t)e * INTER + n0) * HID;
        outp = abuf; etk = etok + e * TTOK;
    } else {
        int sx = bx - GLU_RT;
        n0 = (sx >> 3) * 128;
        m_start = (sx & 7) * 256; m_stop = m_start + 256;
        obase = 0; Ntot = SINTER;
        Bg = sg + (size_t)n0 * HID;
        Bu = su + (size_t)n0 * HID;
        outp = hbuf;
    }

    // B staging: thread -> row t>>3 (0..127), 8 floats at (t&7)*8 per matrix
    const int brow = t >> 3, bc8 = (t & 7) * 8;
    const float* srcG = Bg + (size_t)brow * HID + bc8;
    const float* srcU = Bu + (size_t)brow * HID + bc8;
    const unsigned wBo = swz((unsigned)(brow * 128 + bc8 * 2));

    unsigned aoff[2][2], boff[4][2];
#pragma unroll
    for (int mi = 0; mi < 2; mi++)
#pragma unroll
        for (int ks = 0; ks < 2; ks++)
            aoff[mi][ks] = swz((unsigned)((wm * 32 + mi * 16 + fr) * 128 + ks * 64 + fo * 16));
#pragma unroll
    for (int nj = 0; nj < 4; nj++)
#pragma unroll
        for (int ks = 0; ks < 2; ks++)
            boff[nj][ks] = swz((unsigned)((wn * 64 + nj * 16 + fr) * 128 + ks * 64 + fo * 16));

    const int arow_off = lane >> 3;
    const int achunk = (lane & 7) ^ arow_off;

    for (int m0 = m_start; m0 < m_stop; m0 += 256) {
        const int rv = min(m_stop - m0, 256);
        const unsigned short* srcA[2];
#pragma unroll
        for (int j = 0; j < 2; j++) {
            int r = w * 16 + j * 8 + arow_off;
            int rr = r < rv ? r : rv - 1;
            int tok = routed ? (etk[m0 + rr] >> 1) : (m0 + rr);
            srcA[j] = xb + (size_t)tok * HID + achunk * 8;
        }

        f32x4 ag[2][4], au[2][4];
#pragma unroll
        for (int mi = 0; mi < 2; mi++)
#pragma unroll
            for (int nj = 0; nj < 4; nj++) { ag[mi][nj] = {0.f,0.f,0.f,0.f}; au[mi][nj] = {0.f,0.f,0.f,0.f}; }

        // prologue: A(0) -> buf0, B(0) -> regs
#pragma unroll
        for (int j = 0; j < 2; j++)
            gload16(srcA[j], (char*)sA + w * 2048 + j * 1024);
        float4 gC0 = *(const float4*)(srcG),     gC1 = *(const float4*)(srcG + 4);
        float4 uC0 = *(const float4*)(srcU),     uC1 = *(const float4*)(srcU + 4);
        float4 gN0, gN1, uN0, uN1;

        for (int kk = 0; kk < HID / BK; ++kk) {
            const int cur = kk & 1;
            bsync();                       // all waves done reading LDS of iter kk-1
            if (kk + 1 < HID / BK) {
                const int k0n = (kk + 1) * BK;
#pragma unroll
                for (int j = 0; j < 2; j++)
                    gload16(srcA[j] + k0n, (char*)sA + (cur ^ 1) * 32768 + w * 2048 + j * 1024);
                gN0 = *(const float4*)(srcG + k0n); gN1 = *(const float4*)(srcG + k0n + 4);
                uN0 = *(const float4*)(srcU + k0n); uN1 = *(const float4*)(srcU + k0n + 4);
            }
            __builtin_amdgcn_sched_barrier(0);
            {   // ds_write B(kk) from carried regs (compiler emits counted vmcnt)
                bf16x8 vg, vu;
                vg[0]=(short)f2bf(gC0.x); vg[1]=(short)f2bf(gC0.y); vg[2]=(short)f2bf(gC0.z); vg[3]=(short)f2bf(gC0.w);
                vg[4]=(short)f2bf(gC1.x); vg[5]=(short)f2bf(gC1.y); vg[6]=(short)f2bf(gC1.z); vg[7]=(short)f2bf(gC1.w);
                vu[0]=(short)f2bf(uC0.x); vu[1]=(short)f2bf(uC0.y); vu[2]=(short)f2bf(uC0.z); vu[3]=(short)f2bf(uC0.w);
                vu[4]=(short)f2bf(uC1.x); vu[5]=(short)f2bf(uC1.y); vu[6]=(short)f2bf(uC1.z); vu[7]=(short)f2bf(uC1.w);
                *(bf16x8*)((char*)sBg + wBo) = vg;
                *(bf16x8*)((char*)sBu + wBo) = vu;
            }
            WAIT_LGKM0;
            bsync();                       // A(kk) + B(kk) visible to all waves
            const char* sAc = (const char*)sA + cur * 32768;
#pragma unroll
            for (int ks = 0; ks < 2; ++ks) {
                bf16x8 af[2], gf[4], uf[4];
#pragma unroll
                for (int mi = 0; mi < 2; mi++) af[mi] = *(const bf16x8*)(sAc + aoff[mi][ks]);
#pragma unroll
                for (int nj = 0; nj < 4; nj++) {
                    gf[nj] = *(const bf16x8*)((const char*)sBg + boff[nj][ks]);
                    uf[nj] = *(const bf16x8*)((const char*)sBu + boff[nj][ks]);
                }
#pragma unroll
                for (int mi = 0; mi < 2; mi++)
#pragma unroll
                    for (int nj = 0; nj < 4; nj++) {
                        ag[mi][nj] = MFMA16(af[mi], gf[nj], ag[mi][nj]);
                        au[mi][nj] = MFMA16(af[mi], uf[nj], au[mi][nj]);
                    }
            }
            gC0 = gN0; gC1 = gN1; uC0 = uN0; uC1 = uN1;
        }

        // epilogue: h = silu(g)*u -> stage bf16 [256][128] over sA -> coalesced sweep
        bsync();                           // final MFMA reads done before overwriting sA
        char* sH = (char*)sA;
#pragma unroll
        for (int mi = 0; mi < 2; mi++)
#pragma unroll
            for (int jj = 0; jj < 4; jj++) {
                int r = wm * 32 + mi * 16 + fo * 4 + jj;
#pragma unroll
                for (int nj = 0; nj < 4; nj++) {
                    int c = wn * 64 + nj * 16 + fr;
                    float g = ag[mi][nj][jj];
                    float u = au[mi][nj][jj];
                    float h = (g / (1.f + __expf(-g))) * u;
                    *(unsigned short*)(sH + swz256((unsigned)(r * 256 + c * 2))) = f2bf(h);
                }
            }
        WAIT_LGKM0;
        bsync();
#pragma unroll
        for (int q = 0; q < 4; q++) {
            int idx = q * 1024 + t;
            int r = idx >> 4, c16 = idx & 15;
            if (r < rv) {
                uint4 v = *(const uint4*)(sH + swz256((unsigned)(r * 256 + c16 * 16)));
                *(uint4*)(outp + (size_t)(obase + m0 + r) * Ntot + n0 + c16 * 8) = v;
            }
        }
        bsync();
    }
}

// Down GEMM. BM=256, BN=256, BK=64, 1024 thr / 16 waves (4m x 4n).
__global__ __launch_bounds__(1024, 4) void k_down17(
    const unsigned short* __restrict__ abuf, const unsigned short* __restrict__ hbuf,
    const float* __restrict__ wd, const float* __restrict__ sd,
    unsigned short* __restrict__ slots,
    const int* __restrict__ cnt, const int* __restrict__ offs,
    const int* __restrict__ etok, const float* __restrict__ ew) {
    __shared__ alignas(16) unsigned short sA[2][256 * BK];  // 2 x 32 KB
    __shared__ alignas(16) unsigned short sB[256 * BK];     // 32 KB

    const int bx = blockIdx.x, t = threadIdx.x;
    const int lane = t & 63, w = t >> 6;
    const int wm = w >> 2, wn = w & 3;
    const int fr = lane & 15, fo = lane >> 4;

    const bool routed = bx >= DWN_SH;
    int n0, m_start, m_stop, K, KT;
    const float* W;
    const unsigned short* Abuf;
    size_t arow0 = 0;
    const int* etk = nullptr; const float* ewe = nullptr;
    if (routed) {
        int rx = bx - DWN_SH;
        int e = rx >> 3; n0 = (rx & 7) * 256;
        int M = cnt[e];
        if (M <= 0) return;
        m_start = 0; m_stop = M;
        K = INTER; KT = INTER / BK;
        W = wd + (size_t)e * HID * INTER + (size_t)n0 * INTER;
        Abuf = abuf; arow0 = offs[e];
        etk = etok + e * TTOK; ewe = ew + e * TTOK;
    } else {
        n0 = (bx >> 3) * 256;
        m_start = (bx & 7) * 256; m_stop = m_start + 256;
        K = SINTER; KT = SINTER / BK;
        W = sd + (size_t)n0 * SINTER;
        Abuf = hbuf;
    }

    // B staging: thread -> row t>>2 (0..255), 16 floats at (t&3)*16
    const int brow = t >> 2, bc16 = (t & 3) * 16;
    const float* srcB = W + (size_t)brow * K + bc16;
    const unsigned wBo0 = swz((unsigned)(brow * 128 + bc16 * 2));
    const unsigned wBo1 = swz((unsigned)(brow * 128 + bc16 * 2 + 16));

    unsigned aoff[4][2], boff[4][2];
#pragma unroll
    for (int mi = 0; mi < 4; mi++)
#pragma unroll
        for (int ks = 0; ks < 2; ks++)
            aoff[mi][ks] = swz((unsigned)((wm * 64 + mi * 16 + fr) * 128 + ks * 64 + fo * 16));
#pragma unroll
    for (int nj = 0; nj < 4; nj++)
#pragma unroll
        for (int ks = 0; ks < 2; ks++)
            boff[nj][ks] = swz((unsigned)((wn * 64 + nj * 16 + fr) * 128 + ks * 64 + fo * 16));

    const int arow_off = lane >> 3;
    const int achunk = (lane & 7) ^ arow_off;

    for (int m0 = m_start; m0 < m_stop; m0 += 256) {
        const int rv = min(m_stop - m0, 256);
        const unsigned short* srcA[2];
#pragma unroll
        for (int j = 0; j < 2; j++) {
            int r = w * 16 + j * 8 + arow_off;
            int rr = r < rv ? r : rv - 1;
            srcA[j] = Abuf + (arow0 + m0 + rr) * (size_t)K + achunk * 8;
        }

        f32x4 ac[4][4];
#pragma unroll
        for (int mi = 0; mi < 4; mi++)
#pragma unroll
            for (int nj = 0; nj < 4; nj++) ac[mi][nj] = {0.f, 0.f, 0.f, 0.f};

        // prologue
#pragma unroll
        for (int j = 0; j < 2; j++)
            gload16(srcA[j], (char*)sA + w * 2048 + j * 1024);
        float4 bC0 = *(const float4*)(srcB),      bC1 = *(const float4*)(srcB + 4);
        float4 bC2 = *(const float4*)(srcB + 8),  bC3 = *(const float4*)(srcB + 12);
        float4 bN0, bN1, bN2, bN3;

        for (int kk = 0; kk < KT; ++kk) {
            const int cur = kk & 1;
            bsync();
            if (kk + 1 < KT) {
                const int k0n = (kk + 1) * BK;
#pragma unroll
                for (int j = 0; j < 2; j++)
                    gload16(srcA[j] + k0n, (char*)sA + (cur ^ 1) * 32768 + w * 2048 + j * 1024);
                bN0 = *(const float4*)(srcB + k0n);      bN1 = *(const float4*)(srcB + k0n + 4);
                bN2 = *(const float4*)(srcB + k0n + 8);  bN3 = *(const float4*)(srcB + k0n + 12);
            }
            __builtin_amdgcn_sched_barrier(0);
            {
                bf16x8 v0, v1;
                v0[0]=(short)f2bf(bC0.x); v0[1]=(short)f2bf(bC0.y); v0[2]=(short)f2bf(bC0.z); v0[3]=(short)f2bf(bC0.w);
                v0[4]=(short)f2bf(bC1.x); v0[5]=(short)f2bf(bC1.y); v0[6]=(short)f2bf(bC1.z); v0[7]=(short)f2bf(bC1.w);
                v1[0]=(short)f2bf(bC2.x); v1[1]=(short)f2bf(bC2.y); v1[2]=(short)f2bf(bC2.z); v1[3]=(short)f2bf(bC2.w);
                v1[4]=(short)f2bf(bC3.x); v1[5]=(short)f2bf(bC3.y); v1[6]=(short)f2bf(bC3.z); v1[7]=(short)f2bf(bC3.w);
                *(bf16x8*)((char*)sB + wBo0) = v0;
                *(bf16x8*)((char*)sB + wBo1) = v1;
            }
            WAIT_LGKM0;
            bsync();
            const char* sAc = (const char*)sA + cur * 32768;
#pragma unroll
            for (int ks = 0; ks < 2; ++ks) {
                bf16x8 af[4], bf[4];
#pragma unroll
                for (int mi = 0; mi < 4; mi++) af[mi] = *(const bf16x8*)(sAc + aoff[mi][ks]);
#pragma unroll
                for (int nj = 0; nj < 4; nj++) bf[nj] = *(const bf16x8*)((const char*)sB + boff[nj][ks]);
#pragma unroll
                for (int mi = 0; mi < 4; mi++)
#pragma unroll
                    for (int nj = 0; nj < 4; nj++)
                        ac[mi][nj] = MFMA16(af[mi], bf[nj], ac[mi][nj]);
            }
            bC0 = bN0; bC1 = bN1; bC2 = bN2; bC3 = bN3;
        }

        // epilogue: 2 passes of 128 cols; scale, stage bf16 [256][128] over sA, sweep
        bsync();
        char* sH = (char*)sA;
#pragma unroll
        for (int p = 0; p < 2; p++) {
            if ((wn >> 1) == p) {
#pragma unroll
                for (int mi = 0; mi < 4; mi++)
#pragma unroll
                    for (int jj = 0; jj < 4; jj++) {
                        int r = wm * 64 + mi * 16 + fo * 4 + jj;
                        float wt = 1.f;
                        if (routed) wt = (r < rv) ? ewe[m0 + r] : 0.f;
#pragma unroll
                        for (int nj = 0; nj < 4; nj++) {
                            int c = (wn & 1) * 64 + nj * 16 + fr;
                            *(unsigned short*)(sH + swz256((unsigned)(r * 256 + c * 2))) =
                                f2bf(ac[mi][nj][jj] * wt);
                        }
                    }
            }
            WAIT_LGKM0;
            bsync();
#pragma unroll
            for (int q = 0; q < 4; q++) {
                int idx = q * 1024 + t;
                int r = idx >> 4, c16 = idx & 15;
                if (r < rv) {
                    uint4 v = *(const uint4*)(sH + swz256((unsigned)(r * 256 + c16 * 16)));
                    int tok, slice;
                    if (routed) { int entry = etk[m0 + r]; tok = entry >> 1; slice = entry & 1; }
                    else        { tok = m0 + r; slice = 2; }
                    *(uint4*)(slots + ((size_t)slice * TTOK + tok) * HID + n0 + p * 128 + c16 * 8) = v;
                }
            }
            bsync();
        }
    }
}

__global__ __launch_bounds__(256) void k_final(float* __restrict__ out,
                                               const unsigned short* __restrict__ slots) {
    size_t i = ((size_t)blockIdx.x * 256 + threadIdx.x) * 8;
    u16x8 s0 = *(const u16x8*)(slots + i);
    u16x8 s1 = *(const u16x8*)(slots + (size_t)TTOK * HID + i);
    u16x8 s2 = *(const u16x8*)(slots + (size_t)2 * TTOK * HID + i);
    float4 o0, o1;
    o0.x = bf2f(s0[0]) + bf2f(s1[0]) + bf2f(s2[0]);
    o0.y = bf2f(s0[1]) + bf2f(s1[1]) + bf2f(s2[1]);
    o0.z = bf2f(s0[2]) + bf2f(s1[2]) + bf2f(s2[2]);
    o0.w = bf2f(s0[3]) + bf2f(s1[3]) + bf2f(s2[3]);
    o1.x = bf2f(s0[4]) + bf2f(s1[4]) + bf2f(s2[4]);
    o1.y = bf2f(s0[5]) + bf2f(s1[5]) + bf2f(s2[5]);
    o1.z = bf2f(s0[6]) + bf2f(s1[6]) + bf2f(s2[6]);
    o1.w = bf2f(s0[7]) + bf2f(s1[7]) + bf2f(s2[7]);
    *(float4*)(out + i) = o0;
    *(float4*)(out + i + 4) = o1;
}

extern "C" void kernel_launch(void* const* d_in, const int* in_sizes, int n_in,
                              void* d_out, int out_size, void* d_ws, size_t ws_size,
                              hipStream_t stream) {
    const float* x = (const float*)d_in[0];
    const float* gate_w = (const float*)d_in[1];
    const float* cls_w = (const float*)d_in[2];
    const float* escale = (const float*)d_in[3];
    const float* ebias = (const float*)d_in[4];
    const float* wg = (const float*)d_in[5];
    const float* wu = (const float*)d_in[6];
    const float* wd = (const float*)d_in[7];
    const float* sg = (const float*)d_in[8];
    const float* su = (const float*)d_in[9];
    const float* sd = (const float*)d_in[10];
    float* out = (float*)d_out;

    char* ws = (char*)d_ws;
    size_t o = 0;
    auto alloc = [&](size_t bytes) {
        char* p = ws + o;
        o += (bytes + 255) & ~(size_t)255;
        return p;
    };
    unsigned short* xb    = (unsigned short*)alloc((size_t)TTOK * HID * 2);
    unsigned short* hbuf  = (unsigned short*)alloc((size_t)TTOK * SINTER * 2);
    unsigned short* abuf  = (unsigned short*)alloc((size_t)2 * TTOK * INTER * 2);
    unsigned short* slots = (unsigned short*)alloc((size_t)3 * TTOK * HID * 2);
    int* cnt              = (int*)alloc(256);
    int* offs             = (int*)alloc(256);
    int* etok             = (int*)alloc((size_t)NEXP * TTOK * 4);
    float* ew             = (float*)alloc((size_t)NEXP * TTOK * 4);

    k_zero<<<1, 64, 0, stream>>>(cnt);
    k_router<<<512, 256, 0, stream>>>(x, gate_w, cls_w, escale, ebias, cnt, etok, ew, xb);
    k_offsets<<<1, 64, 0, stream>>>(cnt, offs);
    k_glu17<<<GLU_RT + GLU_SH, 1024, 0, stream>>>(
        xb, wg, wu, sg, su, abuf, hbuf, cnt, offs, etok);
    k_down17<<<DWN_SH + DWN_RT, 1024, 0, stream>>>(
        abuf, hbuf, wd, sd, slots, cnt, offs, etok, ew);
    k_final<<<2048, 256, 0, stream>>>(out, slots);
}

// Round 18
// 1016.706 us; speedup vs baseline: 1.0073x; 1.0073x over previous
//
#include <hip/hip_runtime.h>

#define HID 2048
#define INTER 1408
#define NEXP 14
#define SINTER 2816
#define TTOK 2048
#define BK 64

#define GLU_RT 154   // 14 e x 11 nt (routed first)
#define GLU_SH 176   // 22 nt x 8 m-slices (256 rows each)
#define DWN_SH 64    // 8 nt x 8 m-slices
#define DWN_RT 112   // 14 e x 8 nt

typedef short bf16x8 __attribute__((ext_vector_type(8)));
typedef float f32x4 __attribute__((ext_vector_type(4)));
typedef unsigned short u16x8 __attribute__((ext_vector_type(8)));

__device__ __forceinline__ unsigned short f2bf(float f) {
    __bf16 b = (__bf16)f;
    return __builtin_bit_cast(unsigned short, b);
}
__device__ __forceinline__ float bf2f(unsigned short u) {
    unsigned v = (unsigned)u << 16;
    return __builtin_bit_cast(float, v);
}
// proven conflict-free swizzles: 128B rows (K-tiles), 256B rows (epilogue)
__device__ __forceinline__ unsigned swz(unsigned b)    { return b ^ (((b >> 7) & 7u) << 4); }
__device__ __forceinline__ unsigned swz256(unsigned b) { return b ^ (((b >> 8) & 7u) << 4); }

__device__ __forceinline__ void gload16(const void* g, void* l) {
    __builtin_amdgcn_global_load_lds((__attribute__((address_space(1))) void*)g,
                                     (__attribute__((address_space(3))) void*)l, 16, 0, 0);
}
__device__ __forceinline__ void bsync() {
    __builtin_amdgcn_sched_barrier(0);
    __builtin_amdgcn_s_barrier();
    __builtin_amdgcn_sched_barrier(0);
}
#define WAIT_LGKM0 asm volatile("s_waitcnt lgkmcnt(0)" ::: "memory")
#define MFMA16(a, b, c) __builtin_amdgcn_mfma_f32_16x16x32_bf16(a, b, c, 0, 0, 0)

__global__ void k_zero(int* cnt) {
    if ((int)threadIdx.x < NEXP) cnt[threadIdx.x] = 0;
}

// Router, vectorized (R11-proven) + fused x->bf16 store.
__global__ __launch_bounds__(256, 4) void k_router(
    const float* __restrict__ x,
    const float* __restrict__ gate_w, const float* __restrict__ cls_w,
    const float* __restrict__ escale, const float* __restrict__ ebias,
    int* __restrict__ cnt, int* __restrict__ etok, float* __restrict__ ew,
    unsigned short* __restrict__ xb) {
    const int lane = threadIdx.x & 63;
    const int tok = blockIdx.x * 4 + (threadIdx.x >> 6);
    const float* xr = x + (size_t)tok * HID + lane * 4;
    float4 xv[8];
#pragma unroll
    for (int i = 0; i < 8; i++) xv[i] = *(const float4*)(xr + i * 256);
    unsigned short* xbr = xb + (size_t)tok * HID + lane * 4;
#pragma unroll
    for (int i = 0; i < 8; i++) {
        ushort4 v;
        v.x = f2bf(xv[i].x); v.y = f2bf(xv[i].y);
        v.z = f2bf(xv[i].z); v.w = f2bf(xv[i].w);
        *(ushort4*)(xbr + i * 256) = v;
    }

    float sc[NEXP];
    float mx = 0.f;
#pragma unroll
    for (int e = 0; e < NEXP; e++) {
        const float* cw = cls_w + (size_t)e * HID + lane * 4;
        const float* gw = gate_w + (size_t)e * HID + lane * 4;
        float pc = 0.f, pg = 0.f;
        {
            float4 cv[8];
#pragma unroll
            for (int i = 0; i < 8; i++) cv[i] = *(const float4*)(cw + i * 256);
#pragma unroll
            for (int i = 0; i < 8; i++) {
                pc = fmaf(xv[i].x, cv[i].x, pc);
                pc = fmaf(xv[i].y, cv[i].y, pc);
                pc = fmaf(xv[i].z, cv[i].z, pc);
                pc = fmaf(xv[i].w, cv[i].w, pc);
            }
        }
        {
            float4 gv[8];
#pragma unroll
            for (int i = 0; i < 8; i++) gv[i] = *(const float4*)(gw + i * 256);
#pragma unroll
            for (int i = 0; i < 8; i++) {
                pg = fmaf(xv[i].x, gv[i].x, pg);
                pg = fmaf(xv[i].y, gv[i].y, pg);
                pg = fmaf(xv[i].z, gv[i].z, pg);
                pg = fmaf(xv[i].w, gv[i].w, pg);
            }
        }
#pragma unroll
        for (int o = 32; o >= 1; o >>= 1) {
            pc += __shfl_xor(pc, o);
            pg += __shfl_xor(pg, o);
        }
        float lg = pc * (pg / (1.f + __expf(-pg)));
        sc[e] = fabsf(lg);
        mx = fmaxf(mx, sc[e]);
    }
    float s = 0.f;
#pragma unroll
    for (int e = 0; e < NEXP; e++) { sc[e] = __expf(sc[e] - mx); s += sc[e]; }
    float inv = 1.f / s;
    int i1 = -1, i2 = -1;
    float b1 = -1e30f, b2 = -1e30f, v1 = 0.f, v2 = 0.f;
#pragma unroll
    for (int e = 0; e < NEXP; e++) {
        float sv = sc[e] * inv;
        float b = sv + ebias[e];
        if (b > b1) { b2 = b1; i2 = i1; v2 = v1; b1 = b; i1 = e; v1 = sv; }
        else if (b > b2) { b2 = b; i2 = e; v2 = sv; }
    }
    if (lane == 0) {
        float w1 = 1.f + v1 * escale[i1];
        float w2 = 1.f + v2 * escale[i2];
        int p1 = atomicAdd(&cnt[i1], 1);
        etok[i1 * TTOK + p1] = tok * 2;     ew[i1 * TTOK + p1] = w1;
        int p2 = atomicAdd(&cnt[i2], 1);
        etok[i2 * TTOK + p2] = tok * 2 + 1; ew[i2 * TTOK + p2] = w2;
    }
}

__global__ void k_offsets(const int* __restrict__ cnt, int* __restrict__ offs) {
    if (threadIdx.x == 0) {
        int a = 0;
        for (int e = 0; e < NEXP; e++) { offs[e] = a; a += cnt[e]; }
    }
}

// Gate+up GEMM. BM=256, BN=128(G)+128(U), BK=64, 1024 thr / 16 waves (8m x 2n).
// launch_bounds(1024,2): raise arch-VGPR cap so the 32-reg B carry doesn't spill.
__global__ __launch_bounds__(1024, 2) void k_glu18(
    const unsigned short* __restrict__ xb,
    const float* __restrict__ wg, const float* __restrict__ wu,
    const float* __restrict__ sg, const float* __restrict__ su,
    unsigned short* __restrict__ abuf, unsigned short* __restrict__ hbuf,
    const int* __restrict__ cnt, const int* __restrict__ offs,
    const int* __restrict__ etok) {
    __shared__ alignas(16) unsigned short sA[2][256 * BK];  // 2 x 32 KB
    __shared__ alignas(16) unsigned short sBg[128 * BK];    // 16 KB
    __shared__ alignas(16) unsigned short sBu[128 * BK];    // 16 KB

    const int bx = blockIdx.x, t = threadIdx.x;
    const int lane = t & 63, w = t >> 6;
    const int wm = w >> 1, wn = w & 1;
    const int fr = lane & 15, fo = lane >> 4;

    const bool routed = bx < GLU_RT;
    int n0, m_start, m_stop, obase, Ntot;
    const float *Bg, *Bu;
    unsigned short* outp;
    const int* etk = nullptr;
    if (routed) {
        int e = bx / 11; n0 = (bx % 11) * 128;
        int M = cnt[e];
        if (M <= 0) return;
        m_start = 0; m_stop = M; obase = offs[e]; Ntot = INTER;
        Bg = wg + ((size_t)e * INTER + n0) * HID;
        Bu = wu + ((size_t)e * INTER + n0) * HID;
        outp = abuf; etk = etok + e * TTOK;
    } else {
        int sx = bx - GLU_RT;
        n0 = (sx >> 3) * 128;
        m_start = (sx & 7) * 256; m_stop = m_start + 256;
        obase = 0; Ntot = SINTER;
        Bg = sg + (size_t)n0 * HID;
        Bu = su + (size_t)n0 * HID;
        outp = hbuf;
    }

    const int brow = t >> 3, bc8 = (t & 7) * 8;
    const float* srcG = Bg + (size_t)brow * HID + bc8;
    const float* srcU = Bu + (size_t)brow * HID + bc8;
    const unsigned wBo = swz((unsigned)(brow * 128 + bc8 * 2));

    unsigned aoff[2][2], boff[4][2];
#pragma unroll
    for (int mi = 0; mi < 2; mi++)
#pragma unroll
        for (int ks = 0; ks < 2; ks++)
            aoff[mi][ks] = swz((unsigned)((wm * 32 + mi * 16 + fr) * 128 + ks * 64 + fo * 16));
#pragma unroll
    for (int nj = 0; nj < 4; nj++)
#pragma unroll
        for (int ks = 0; ks < 2; ks++)
            boff[nj][ks] = swz((unsigned)((wn * 64 + nj * 16 + fr) * 128 + ks * 64 + fo * 16));

    const int arow_off = lane >> 3;
    const int achunk = (lane & 7) ^ arow_off;

    for (int m0 = m_start; m0 < m_stop; m0 += 256) {
        const int rv = min(m_stop - m0, 256);
        const unsigned short* srcA[2];
#pragma unroll
        for (int j = 0; j < 2; j++) {
            int r = w * 16 + j * 8 + arow_off;
            int rr = r < rv ? r : rv - 1;
            int tok = routed ? (etk[m0 + rr] >> 1) : (m0 + rr);
            srcA[j] = xb + (size_t)tok * HID + achunk * 8;
        }

        f32x4 ag[2][4], au[2][4];
#pragma unroll
        for (int mi = 0; mi < 2; mi++)
#pragma unroll
            for (int nj = 0; nj < 4; nj++) { ag[mi][nj] = {0.f,0.f,0.f,0.f}; au[mi][nj] = {0.f,0.f,0.f,0.f}; }

        // prologue: A(0) -> buf0, B(0) -> regs
#pragma unroll
        for (int j = 0; j < 2; j++)
            gload16(srcA[j], (char*)sA + w * 2048 + j * 1024);
        float4 gC0 = *(const float4*)(srcG),     gC1 = *(const float4*)(srcG + 4);
        float4 uC0 = *(const float4*)(srcU),     uC1 = *(const float4*)(srcU + 4);
        float4 gN0, gN1, uN0, uN1;

        for (int kk = 0; kk < HID / BK; ++kk) {
            const int cur = kk & 1;
            bsync();                       // all waves done reading LDS of iter kk-1
            if (kk + 1 < HID / BK) {
                const int k0n = (kk + 1) * BK;
#pragma unroll
                for (int j = 0; j < 2; j++)
                    gload16(srcA[j] + k0n, (char*)sA + (cur ^ 1) * 32768 + w * 2048 + j * 1024);
                gN0 = *(const float4*)(srcG + k0n); gN1 = *(const float4*)(srcG + k0n + 4);
                uN0 = *(const float4*)(srcU + k0n); uN1 = *(const float4*)(srcU + k0n + 4);
            }
            __builtin_amdgcn_sched_barrier(0);
            {   // ds_write B(kk) from carried regs (compiler emits counted vmcnt)
                bf16x8 vg, vu;
                vg[0]=(short)f2bf(gC0.x); vg[1]=(short)f2bf(gC0.y); vg[2]=(short)f2bf(gC0.z); vg[3]=(short)f2bf(gC0.w);
                vg[4]=(short)f2bf(gC1.x); vg[5]=(short)f2bf(gC1.y); vg[6]=(short)f2bf(gC1.z); vg[7]=(short)f2bf(gC1.w);
                vu[0]=(short)f2bf(uC0.x); vu[1]=(short)f2bf(uC0.y); vu[2]=(short)f2bf(uC0.z); vu[3]=(short)f2bf(uC0.w);
                vu[4]=(short)f2bf(uC1.x); vu[5]=(short)f2bf(uC1.y); vu[6]=(short)f2bf(uC1.z); vu[7]=(short)f2bf(uC1.w);
                *(bf16x8*)((char*)sBg + wBo) = vg;
                *(bf16x8*)((char*)sBu + wBo) = vu;
            }
            WAIT_LGKM0;
            bsync();                       // A(kk) + B(kk) visible to all waves
            const char* sAc = (const char*)sA + cur * 32768;
#pragma unroll
            for (int ks = 0; ks < 2; ++ks) {
                bf16x8 af[2], gf[4], uf[4];
#pragma unroll
                for (int mi = 0; mi < 2; mi++) af[mi] = *(const bf16x8*)(sAc + aoff[mi][ks]);
#pragma unroll
                for (int nj = 0; nj < 4; nj++) {
                    gf[nj] = *(const bf16x8*)((const char*)sBg + boff[nj][ks]);
                    uf[nj] = *(const bf16x8*)((const char*)sBu + boff[nj][ks]);
                }
#pragma unroll
                for (int mi = 0; mi < 2; mi++)
#pragma unroll
                    for (int nj = 0; nj < 4; nj++) {
                        ag[mi][nj] = MFMA16(af[mi], gf[nj], ag[mi][nj]);
                        au[mi][nj] = MFMA16(af[mi], uf[nj], au[mi][nj]);
                    }
            }
            gC0 = gN0; gC1 = gN1; uC0 = uN0; uC1 = uN1;
        }

        // epilogue: h = silu(g)*u -> stage bf16 [256][128] over sA -> coalesced sweep
        bsync();                           // final MFMA reads done before overwriting sA
        char* sH = (char*)sA;
#pragma unroll
        for (int mi = 0; mi < 2; mi++)
#pragma unroll
            for (int jj = 0; jj < 4; jj++) {
                int r = wm * 32 + mi * 16 + fo * 4 + jj;
#pragma unroll
                for (int nj = 0; nj < 4; nj++) {
                    int c = wn * 64 + nj * 16 + fr;
                    float g = ag[mi][nj][jj];
                    float u = au[mi][nj][jj];
                    float h = (g / (1.f + __expf(-g))) * u;
                    *(unsigned short*)(sH + swz256((unsigned)(r * 256 + c * 2))) = f2bf(h);
                }
            }
        WAIT_LGKM0;
        bsync();
#pragma unroll
        for (int q = 0; q < 4; q++) {
            int idx = q * 1024 + t;
            int r = idx >> 4, c16 = idx & 15;
            if (r < rv) {
                uint4 v = *(const uint4*)(sH + swz256((unsigned)(r * 256 + c16 * 16)));
                *(uint4*)(outp + (size_t)(obase + m0 + r) * Ntot + n0 + c16 * 8) = v;
            }
        }
        bsync();
    }
}

// Down GEMM. BM=256, BN=256, BK=64, 1024 thr / 16 waves (4m x 4n).
__global__ __launch_bounds__(1024, 2) void k_down18(
    const unsigned short* __restrict__ abuf, const unsigned short* __restrict__ hbuf,
    const float* __restrict__ wd, const float* __restrict__ sd,
    unsigned short* __restrict__ slots,
    const int* __restrict__ cnt, const int* __restrict__ offs,
    const int* __restrict__ etok, const float* __restrict__ ew) {
    __shared__ alignas(16) unsigned short sA[2][256 * BK];  // 2 x 32 KB
    __shared__ alignas(16) unsigned short sB[256 * BK];     // 32 KB

    const int bx = blockIdx.x, t = threadIdx.x;
    const int lane = t & 63, w = t >> 6;
    const int wm = w >> 2, wn = w & 3;
    const int fr = lane & 15, fo = lane >> 4;

    const bool routed = bx >= DWN_SH;
    int n0, m_start, m_stop, K, KT;
    const float* W;
    const unsigned short* Abuf;
    size_t arow0 = 0;
    const int* etk = nullptr; const float* ewe = nullptr;
    if (routed) {
        int rx = bx - DWN_SH;
        int e = rx >> 3; n0 = (rx & 7) * 256;
        int M = cnt[e];
        if (M <= 0) return;
        m_start = 0; m_stop = M;
        K = INTER; KT = INTER / BK;
        W = wd + (size_t)e * HID * INTER + (size_t)n0 * INTER;
        Abuf = abuf; arow0 = offs[e];
        etk = etok + e * TTOK; ewe = ew + e * TTOK;
    } else {
        n0 = (bx >> 3) * 256;
        m_start = (bx & 7) * 256; m_stop = m_start + 256;
        K = SINTER; KT = SINTER / BK;
        W = sd + (size_t)n0 * SINTER;
        Abuf = hbuf;
    }

    const int brow = t >> 2, bc16 = (t & 3) * 16;
    const float* srcB = W + (size_t)brow * K + bc16;
    const unsigned wBo0 = swz((unsigned)(brow * 128 + bc16 * 2));
    const unsigned wBo1 = swz((unsigned)(brow * 128 + bc16 * 2 + 16));

    unsigned aoff[4][2], boff[4][2];
#pragma unroll
    for (int mi = 0; mi < 4; mi++)
#pragma unroll
        for (int ks = 0; ks < 2; ks++)
            aoff[mi][ks] = swz((unsigned)((wm * 64 + mi * 16 + fr) * 128 + ks * 64 + fo * 16));
#pragma unroll
    for (int nj = 0; nj < 4; nj++)
#pragma unroll
        for (int ks = 0; ks < 2; ks++)
            boff[nj][ks] = swz((unsigned)((wn * 64 + nj * 16 + fr) * 128 + ks * 64 + fo * 16));

    const int arow_off = lane >> 3;
    const int achunk = (lane & 7) ^ arow_off;

    for (int m0 = m_start; m0 < m_stop; m0 += 256) {
        const int rv = min(m_stop - m0, 256);
        const unsigned short* srcA[2];
#pragma unroll
        for (int j = 0; j < 2; j++) {
            int r = w * 16 + j * 8 + arow_off;
            int rr = r < rv ? r : rv - 1;
            srcA[j] = Abuf + (arow0 + m0 + rr) * (size_t)K + achunk * 8;
        }

        f32x4 ac[4][4];
#pragma unroll
        for (int mi = 0; mi < 4; mi++)
#pragma unroll
            for (int nj = 0; nj < 4; nj++) ac[mi][nj] = {0.f, 0.f, 0.f, 0.f};

#pragma unroll
        for (int j = 0; j < 2; j++)
            gload16(srcA[j], (char*)sA + w * 2048 + j * 1024);
        float4 bC0 = *(const float4*)(srcB),      bC1 = *(const float4*)(srcB + 4);
        float4 bC2 = *(const float4*)(srcB + 8),  bC3 = *(const float4*)(srcB + 12);
        float4 bN0, bN1, bN2, bN3;

        for (int kk = 0; kk < KT; ++kk) {
            const int cur = kk & 1;
            bsync();
            if (kk + 1 < KT) {
                const int k0n = (kk + 1) * BK;
#pragma unroll
                for (int j = 0; j < 2; j++)
                    gload16(srcA[j] + k0n, (char*)sA + (cur ^ 1) * 32768 + w * 2048 + j * 1024);
                bN0 = *(const float4*)(srcB + k0n);      bN1 = *(const float4*)(srcB + k0n + 4);
                bN2 = *(const float4*)(srcB + k0n + 8);  bN3 = *(const float4*)(srcB + k0n + 12);
            }
            __builtin_amdgcn_sched_barrier(0);
            {
                bf16x8 v0, v1;
                v0[0]=(short)f2bf(bC0.x); v0[1]=(short)f2bf(bC0.y); v0[2]=(short)f2bf(bC0.z); v0[3]=(short)f2bf(bC0.w);
                v0[4]=(short)f2bf(bC1.x); v0[5]=(short)f2bf(bC1.y); v0[6]=(short)f2bf(bC1.z); v0[7]=(short)f2bf(bC1.w);
                v1[0]=(short)f2bf(bC2.x); v1[1]=(short)f2bf(bC2.y); v1[2]=(short)f2bf(bC2.z); v1[3]=(short)f2bf(bC2.w);
                v1[4]=(short)f2bf(bC3.x); v1[5]=(short)f2bf(bC3.y); v1[6]=(short)f2bf(bC3.z); v1[7]=(short)f2bf(bC3.w);
                *(bf16x8*)((char*)sB + wBo0) = v0;
                *(bf16x8*)((char*)sB + wBo1) = v1;
            }
            WAIT_LGKM0;
            bsync();
            const char* sAc = (const char*)sA + cur * 32768;
#pragma unroll
            for (int ks = 0; ks < 2; ++ks) {
                bf16x8 af[4], bf[4];
#pragma unroll
                for (int mi = 0; mi < 4; mi++) af[mi] = *(const bf16x8*)(sAc + aoff[mi][ks]);
#pragma unroll
                for (int nj = 0; nj < 4; nj++) bf[nj] = *(const bf16x8*)((const char*)sB + boff[nj][ks]);
#pragma unroll
                for (int mi = 0; mi < 4; mi++)
#pragma unroll
                    for (int nj = 0; nj < 4; nj++)
                        ac[mi][nj] = MFMA16(af[mi], bf[nj], ac[mi][nj]);
            }
            bC0 = bN0; bC1 = bN1; bC2 = bN2; bC3 = bN3;
        }

        // epilogue: 2 passes of 128 cols; scale, stage bf16 [256][128] over sA, sweep
        bsync();
        char* sH = (char*)sA;
#pragma unroll
        for (int p = 0; p < 2; p++) {
            if ((wn >> 1) == p) {
#pragma unroll
                for (int mi = 0; mi < 4; mi++)
#pragma unroll
                    for (int jj = 0; jj < 4; jj++) {
                        int r = wm * 64 + mi * 16 + fo * 4 + jj;
                        float wt = 1.f;
                        if (routed) wt = (r < rv) ? ewe[m0 + r] : 0.f;
#pragma unroll
                        for (int nj = 0; nj < 4; nj++) {
                            int c = (wn & 1) * 64 + nj * 16 + fr;
                            *(unsigned short*)(sH + swz256((unsigned)(r * 256 + c * 2))) =
                                f2bf(ac[mi][nj][jj] * wt);
                        }
                    }
            }
            WAIT_LGKM0;
            bsync();
#pragma unroll
            for (int q = 0; q < 4; q++) {
                int idx = q * 1024 + t;
                int r = idx >> 4, c16 = idx & 15;
                if (r < rv) {
                    uint4 v = *(const uint4*)(sH + swz256((unsigned)(r * 256 + c16 * 16)));
                    int tok, slice;
                    if (routed) { int entry = etk[m0 + r]; tok = entry >> 1; slice = entry & 1; }
                    else        { tok = m0 + r; slice = 2; }
                    *(uint4*)(slots + ((size_t)slice * TTOK + tok) * HID + n0 + p * 128 + c16 * 8) = v;
                }
            }
            bsync();
        }
    }
}

__global__ __launch_bounds__(256) void k_final(float* __restrict__ out,
                                               const unsigned short* __restrict__ slots) {
    size_t i = ((size_t)blockIdx.x * 256 + threadIdx.x) * 8;
    u16x8 s0 = *(const u16x8*)(slots + i);
    u16x8 s1 = *(const u16x8*)(slots + (size_t)TTOK * HID + i);
    u16x8 s2 = *(const u16x8*)(slots + (size_t)2 * TTOK * HID + i);
    float4 o0, o1;
    o0.x = bf2f(s0[0]) + bf2f(s1[0]) + bf2f(s2[0]);
    o0.y = bf2f(s0[1]) + bf2f(s1[1]) + bf2f(s2[1]);
    o0.z = bf2f(s0[2]) + bf2f(s1[2]) + bf2f(s2[2]);
    o0.w = bf2f(s0[3]) + bf2f(s1[3]) + bf2f(s2[3]);
    o1.x = bf2f(s0[4]) + bf2f(s1[4]) + bf2f(s2[4]);
    o1.y = bf2f(s0[5]) + bf2f(s1[5]) + bf2f(s2[5]);
    o1.z = bf2f(s0[6]) + bf2f(s1[6]) + bf2f(s2[6]);
    o1.w = bf2f(s0[7]) + bf2f(s1[7]) + bf2f(s2[7]);
    *(float4*)(out + i) = o0;
    *(float4*)(out + i + 4) = o1;
}

extern "C" void kernel_launch(void* const* d_in, const int* in_sizes, int n_in,
                              void* d_out, int out_size, void* d_ws, size_t ws_size,
                              hipStream_t stream) {
    const float* x = (const float*)d_in[0];
    const float* gate_w = (const float*)d_in[1];
    const float* cls_w = (const float*)d_in[2];
    const float* escale = (const float*)d_in[3];
    const float* ebias = (const float*)d_in[4];
    const float* wg = (const float*)d_in[5];
    const float* wu = (const float*)d_in[6];
    const float* wd = (const float*)d_in[7];
    const float* sg = (const float*)d_in[8];
    const float* su = (const float*)d_in[9];
    const float* sd = (const float*)d_in[10];
    float* out = (float*)d_out;

    char* ws = (char*)d_ws;
    size_t o = 0;
    auto alloc = [&](size_t bytes) {
        char* p = ws + o;
        o += (bytes + 255) & ~(size_t)255;
        return p;
    };
    unsigned short* xb    = (unsigned short*)alloc((size_t)TTOK * HID * 2);
    unsigned short* hbuf  = (unsigned short*)alloc((size_t)TTOK * SINTER * 2);
    unsigned short* abuf  = (unsigned short*)alloc((size_t)2 * TTOK * INTER * 2);
    unsigned short* slots = (unsigned short*)alloc((size_t)3 * TTOK * HID * 2);
    int* cnt              = (int*)alloc(256);
    int* offs             = (int*)alloc(256);
    int* etok             = (int*)alloc((size_t)NEXP * TTOK * 4);
    float* ew             = (float*)alloc((size_t)NEXP * TTOK * 4);

    k_zero<<<1, 64, 0, stream>>>(cnt);
    k_router<<<512, 256, 0, stream>>>(x, gate_w, cls_w, escale, ebias, cnt, etok, ew, xb);
    k_offsets<<<1, 64, 0, stream>>>(cnt, offs);
    k_glu18<<<GLU_RT + GLU_SH, 1024, 0, stream>>>(
        xb, wg, wu, sg, su, abuf, hbuf, cnt, offs, etok);
    k_down18<<<DWN_SH + DWN_RT, 1024, 0, stream>>>(
        abuf, hbuf, wd, sd, slots, cnt, offs, etok, ew);
    k_final<<<2048, 256, 0, stream>>>(out, slots);
}